// Round 5
// baseline (311.013 us; speedup 1.0000x reference)
//
#include <hip/hip_runtime.h>

// Problem dims
#define B_    32
#define CIN   32
#define COUT  64
#define H_    128
#define W_    128
#define HO_   126
#define WO_   126
#define MAXCN 64

typedef __attribute__((ext_vector_type(8))) short short8;
typedef __attribute__((ext_vector_type(4))) float floatx4;

static __device__ __forceinline__ unsigned short f2bf(float f) {
    union { float f; unsigned u; } v; v.f = f;
    unsigned r = v.u + 0x7fff + ((v.u >> 16) & 1);   // round-to-nearest-even
    return (unsigned short)(r >> 16);
}

// async global->LDS, 16 B per lane; LDS dest = wave-uniform base + lane*16
static __device__ __forceinline__ void gld16(const void* g, void* l) {
    __builtin_amdgcn_global_load_lds(
        (const __attribute__((address_space(1))) unsigned int*)g,
        (__attribute__((address_space(3))) unsigned int*)l, 16, 0, 0);
}

// ---------------------------------------------------------------------------
// Fold masked 64-slot bank -> dense bf16 weights, FRAGMENT-ORDER layout:
//   chunk index = (tap*4 + quad)*64 + oc   (16 B chunks of 8 channels)
// slot j feeds channel j%32, active iff j < cn[oc].
// ---------------------------------------------------------------------------
__global__ void fold_bf16(const float* __restrict__ w,
                          const int* __restrict__ cn,
                          unsigned short* __restrict__ wk) {
    int idx = blockIdx.x * 256 + threadIdx.x;        // over 9*64*32 = 18432
    if (idx >= 9 * COUT * CIN) return;
    int c   = idx & 31;
    int oc  = (idx >> 5) & 63;
    int tap = idx >> 11;
    int n = cn[oc];
    float v = 0.0f;
    if (c < n)      v += w[(oc * MAXCN + c) * 9 + tap];
    if (c + 32 < n) v += w[(oc * MAXCN + c + 32) * 9 + tap];
    wk[((tap * 4 + (c >> 3)) * 64 + oc) * 8 + (c & 7)] = f2bf(v);
}

// ---------------------------------------------------------------------------
// x [B][C][H][W] fp32 -> xb [B][H][W][C] bf16 (NHWC).
// ---------------------------------------------------------------------------
__global__ __launch_bounds__(256)
void nchw_to_nhwc_bf16(const float* __restrict__ x,
                       unsigned short* __restrict__ xb) {
    const int b = blockIdx.y, y = blockIdx.x;
    const int t = threadIdx.x;
    const int c8  = t & 3;
    const int xi0 = t >> 2;                          // 0..63
    const float* xp = x + (size_t)b * CIN * H_ * W_ + (size_t)y * W_;
#pragma unroll
    for (int it = 0; it < 2; ++it) {
        const int xi = xi0 + it * 64;
        __align__(16) unsigned short v[8];
#pragma unroll
        for (int j = 0; j < 8; ++j) {
            const int c = c8 * 8 + j;
            v[j] = f2bf(xp[(size_t)c * (H_ * W_) + xi]);
        }
        *(uint4*)(xb + (((size_t)b * H_ + y) * W_ + xi) * CIN + c8 * 8) =
            *(const uint4*)v;
    }
}

// ---------------------------------------------------------------------------
// bias [oc][y][x] -> bnhwc [y][x][oc]  (float4-loadable epilogue bias)
// ---------------------------------------------------------------------------
__global__ __launch_bounds__(256)
void bias_to_nhwc(const float* __restrict__ bias, float* __restrict__ bn) {
    int idx = blockIdx.x * 256 + threadIdx.x;
    int oc = idx & 63;
    int p  = idx >> 6;
    int y  = p / WO_;
    int x  = p - y * WO_;
    bn[idx] = bias[((size_t)oc * HO_ + y) * WO_ + x];
}

// ---------------------------------------------------------------------------
// Stage one 18x18-pixel input tile (1296 16 B chunks) into LDS buffer bsel.
// LDS dest LINEAR in chunk index d; global source is the INVERSE permutation
// of the conflict-free read layout  d = (row*4 + cp)*18 + xc  (m173 pattern).
// 8 waves: wave w covers chunks [w*162, (w+1)*162): 2 full 64-lane gld16 +
// 34-lane tail (exec-masked lanes simply don't issue).
// ---------------------------------------------------------------------------
static __device__ __forceinline__
void stage_tile(const unsigned short* __restrict__ xbi,
                unsigned short* __restrict__ lds,
                int w_id, int lane, int y0, int x0, int bsel) {
    unsigned short* dst = lds + bsel * (1296 * 8);
#pragma unroll
    for (int k = 0; k < 2; ++k) {
        const int base = w_id * 162 + k * 64;
        const int d = base + lane;
        const int q = d / 18, xc = d - q * 18;
        const int row = q >> 2, cp = q & 3;
        int iy = y0 + row; if (iy > H_ - 1) iy = H_ - 1;
        int ix = x0 + xc;  if (ix > W_ - 1) ix = W_ - 1;
        gld16(xbi + (((iy << 7) + ix) * 4 + cp) * 8, dst + base * 8);
    }
    {
        const int base = w_id * 162 + 128;
        if (lane < 34) {
            const int d = base + lane;
            const int q = d / 18, xc = d - q * 18;
            const int row = q >> 2, cp = q & 3;
            int iy = y0 + row; if (iy > H_ - 1) iy = H_ - 1;
            int ix = x0 + xc;  if (ix > W_ - 1) ix = W_ - 1;
            gld16(xbi + (((iy << 7) + ix) * 4 + cp) * 8, dst + base * 8);
        }
    }
}

// ---------------------------------------------------------------------------
// Pipelined implicit-GEMM conv, bf16 MFMA 16x16x32.
//   Block = 4-tile row strip (16 rows x 64 cols) x ALL 64 oc. 8 waves (512
//   threads); wave w owns output rows 2w..2w+1 of each tile (acc[2][4]).
//   Grid 512 = exactly 2 blocks/CU -> 16 waves/CU (4/SIMD) — R3 proved the
//   traffic model (FETCH 23 MB) but was latency-bound at 8 waves/CU; this
//   doubles concurrency with IDENTICAL LDS layout, staging and pipeline.
//   LDS 78336 B: xs double buffer 2x20736 + ws 36864 (weights staged ONCE
//   per block). 2-phase pipeline: issue stage of tile t+1, compute tile t,
//   epilogue, one __syncthreads (vmcnt drain) per tile.
// ---------------------------------------------------------------------------
__global__ __launch_bounds__(512, 4)
void conv_mfma(const unsigned short* __restrict__ xb,
               const unsigned short* __restrict__ wk,
               const float* __restrict__ bnhwc,
               float* __restrict__ out) {
    __shared__ __align__(16) unsigned short lds[4896 * 8];   // 78336 B

    const int s   = blockIdx.x;           // 0..511
    const int img = s >> 4;
    const int ty  = (s >> 1) & 7;
    const int tx0 = (s & 1) * 4;
    const int y0  = ty * 16;
    const int tid = threadIdx.x;
    const int w_id = tid >> 6, lane = tid & 63;
    const int quad = lane >> 4, l16 = lane & 15;

    const unsigned short* xbi = xb + (size_t)img * (H_ * W_ * CIN);

    // ---- stage all 64-oc weights once: 2304 chunks over 8 waves ----
#pragma unroll
    for (int k = 0; k < 4; ++k) {
        const int ch = w_id * 288 + k * 64;
        gld16(wk + (ch + lane) * 8, &lds[(2592 + ch) * 8]);
    }
    {
        const int ch = w_id * 288 + 256;
        if (lane < 32)
            gld16(wk + (ch + lane) * 8, &lds[(2592 + ch) * 8]);
    }
    // ---- stage first tile into buffer 0 ----
    stage_tile(xbi, lds, w_id, lane, y0, tx0 * 16, 0);
    __syncthreads();

    for (int t = 0; t < 4; ++t) {
        const int buf = t & 1;
        if (t < 3)
            stage_tile(xbi, lds, w_id, lane, y0, (tx0 + t + 1) * 16, buf ^ 1);

        const unsigned short* xsb = lds + buf * (1296 * 8);
        const unsigned short* wsb = lds + 2592 * 8;

        floatx4 acc[2][4];
#pragma unroll
        for (int i = 0; i < 2; ++i)
#pragma unroll
            for (int tt = 0; tt < 4; ++tt) acc[i][tt] = (floatx4)0.0f;

#pragma unroll
        for (int kh = 0; kh < 3; ++kh) {
#pragma unroll
            for (int kw = 0; kw < 3; ++kw) {
                const int tap = kh * 3 + kw;
                short8 a[4], bf[2];
#pragma unroll
                for (int tt = 0; tt < 4; ++tt)
                    a[tt] = *(const short8*)&wsb[((tap * 4 + quad) * 64 + tt * 16 + l16) * 8];
#pragma unroll
                for (int i = 0; i < 2; ++i)
                    bf[i] = *(const short8*)&xsb[(((2 * w_id + i + kh) * 4 + quad) * 18 + l16 + kw) * 8];
#pragma unroll
                for (int i = 0; i < 2; ++i)
#pragma unroll
                    for (int tt = 0; tt < 4; ++tt)
                        acc[i][tt] = __builtin_amdgcn_mfma_f32_16x16x32_bf16(a[tt], bf[i], acc[i][tt], 0, 0, 0);
            }
        }

        // ---- epilogue: float4 NHWC bias + guarded quad-coalesced stores ----
        const int col = (tx0 + t) * 16 + l16;
        if (col < WO_) {
#pragma unroll
            for (int i = 0; i < 2; ++i) {
                const int y = y0 + 2 * w_id + i;
                if (y >= HO_) continue;
                const float* bp = bnhwc + ((size_t)y * WO_ + col) * COUT;
#pragma unroll
                for (int tt = 0; tt < 4; ++tt) {
                    const float4 bv = *(const float4*)(bp + tt * 16 + quad * 4);
#pragma unroll
                    for (int r = 0; r < 4; ++r) {
                        const int oc = tt * 16 + quad * 4 + r;
                        out[(((size_t)(img * COUT + oc)) * HO_ + y) * WO_ + col] =
                            acc[i][tt][r] + bv[r];
                    }
                }
            }
        }
        if (t < 3) __syncthreads();
    }
}

// ===========================================================================
// Fallback fp32 path — used only if ws_size is too small.
// ===========================================================================
__global__ void fold_kernel(const float* __restrict__ w,
                            const int* __restrict__ cn,
                            float* __restrict__ kd) {
    int idx = blockIdx.x * blockDim.x + threadIdx.x;
    if (idx >= COUT * CIN * 9) return;
    int t = idx % 9;
    int c = (idx / 9) % CIN;
    int o = idx / (9 * CIN);
    int n = cn[o];
    float v = 0.0f;
    if (c < n)      v += w[(o * MAXCN + c) * 9 + t];
    if (c + 32 < n) v += w[(o * MAXCN + c + 32) * 9 + t];
    kd[idx] = v;
}

__global__ __launch_bounds__(256)
void conv_kernel(const float* __restrict__ x,
                 const float* __restrict__ kd,
                 const float* __restrict__ bias,
                 float* __restrict__ out) {
    __shared__ __align__(16) float xsh[CIN * 18 * 20];
    __shared__ __align__(16) float wsh[16 * 289];
    const int b = blockIdx.z, ocg = blockIdx.y, tile = blockIdx.x;
    const int ty = tile >> 3, txx = tile & 7;
    const int y0 = ty * 16, x0 = txx * 16;
    const int tid = threadIdx.x;
    const float* xbp = x + (size_t)b * CIN * H_ * W_;
    for (int idx = tid; idx < CIN * 18 * 18; idx += 256) {
        int c = idx / 324, rem = idx - c * 324, r = rem / 18, col = rem - r * 18;
        int iy = y0 + r;   if (iy > H_ - 1) iy = H_ - 1;
        int ix = x0 + col; if (ix > W_ - 1) ix = W_ - 1;
        xsh[c * 360 + r * 20 + col] = xbp[(c * H_ + iy) * W_ + ix];
    }
    for (int idx = tid; idx < 16 * 288; idx += 256) {
        int oc = idx / 288, rr = idx - oc * 288;
        wsh[oc * 289 + rr] = kd[(ocg * 16 + oc) * 288 + rr];
    }
    __syncthreads();
    const int oc_l = tid & 15, pb = tid >> 4, pby = pb >> 2, pbx = pb & 3;
    float acc[4][4];
#pragma unroll
    for (int i = 0; i < 4; ++i)
#pragma unroll
        for (int j = 0; j < 4; ++j) acc[i][j] = 0.0f;
    const float* xp = &xsh[(pby * 4) * 20 + pbx * 4];
    const float* wp = &wsh[oc_l * 289];
    for (int c = 0; c < CIN; ++c) {
        float xr[6][6];
#pragma unroll
        for (int r = 0; r < 6; ++r) {
            const float* row = xp + c * 360 + r * 20;
            float4 v4 = *reinterpret_cast<const float4*>(row);
            float2 v2 = *reinterpret_cast<const float2*>(row + 4);
            xr[r][0] = v4.x; xr[r][1] = v4.y; xr[r][2] = v4.z;
            xr[r][3] = v4.w; xr[r][4] = v2.x; xr[r][5] = v2.y;
        }
        float wr[9];
#pragma unroll
        for (int t = 0; t < 9; ++t) wr[t] = wp[c * 9 + t];
#pragma unroll
        for (int kh = 0; kh < 3; ++kh)
#pragma unroll
            for (int kw = 0; kw < 3; ++kw) {
                const float wv = wr[kh * 3 + kw];
#pragma unroll
                for (int i = 0; i < 4; ++i)
#pragma unroll
                    for (int j = 0; j < 4; ++j)
                        acc[i][j] = fmaf(xr[i + kh][j + kw], wv, acc[i][j]);
            }
    }
    const int o = ocg * 16 + oc_l;
    const int yb = y0 + pby * 4, xq0 = x0 + pbx * 4;
    float* ob = out + ((size_t)(b * COUT + o)) * HO_ * WO_;
    const float* bb = bias + (size_t)o * HO_ * WO_;
#pragma unroll
    for (int i = 0; i < 4; ++i) {
        int y = yb + i;
        if (y >= HO_) continue;
#pragma unroll
        for (int j = 0; j < 4; ++j) {
            int xq = xq0 + j;
            if (xq >= WO_) continue;
            ob[y * WO_ + xq] = acc[i][j] + bb[y * WO_ + xq];
        }
    }
}

extern "C" void kernel_launch(void* const* d_in, const int* in_sizes, int n_in,
                              void* d_out, int out_size, void* d_ws, size_t ws_size,
                              hipStream_t stream) {
    const float* x    = (const float*)d_in[0];
    const float* w    = (const float*)d_in[1];
    const float* bias = (const float*)d_in[2];
    const int*   cn   = (const int*)d_in[3];
    float* out = (float*)d_out;

    const size_t XB_BYTES = (size_t)B_ * H_ * W_ * CIN * 2;   // 33554432
    const size_t WK_BYTES = (size_t)9 * COUT * CIN * 2;       // 36864
    const size_t BN_BYTES = (size_t)HO_ * WO_ * COUT * 4;     // 4064256

    if (ws_size >= XB_BYTES + WK_BYTES + BN_BYTES) {
        unsigned short* xbuf = (unsigned short*)d_ws;
        unsigned short* wkb  = (unsigned short*)((char*)d_ws + XB_BYTES);
        float*          bnb  = (float*)((char*)d_ws + XB_BYTES + WK_BYTES);
        fold_bf16<<<72, 256, 0, stream>>>(w, cn, wkb);
        nchw_to_nhwc_bf16<<<dim3(H_, B_), 256, 0, stream>>>(x, xbuf);
        bias_to_nhwc<<<3969, 256, 0, stream>>>(bias, bnb);
        conv_mfma<<<512, 512, 0, stream>>>(xbuf, wkb, bnb, out);
    } else {
        float* kd = (float*)d_ws;                             // 73728 B
        fold_kernel<<<(COUT * CIN * 9 + 255) / 256, 256, 0, stream>>>(w, cn, kd);
        dim3 grid(64, 4, B_);
        conv_kernel<<<grid, 256, 0, stream>>>(x, kd, bias, out);
    }
}

// Round 6
// 288.231 us; speedup vs baseline: 1.0790x; 1.0790x over previous
//
#include <hip/hip_runtime.h>

// Problem dims
#define B_    32
#define CIN   32
#define COUT  64
#define H_    128
#define W_    128
#define HO_   126
#define WO_   126
#define MAXCN 64

typedef __attribute__((ext_vector_type(8))) short short8;
typedef __attribute__((ext_vector_type(4))) float floatx4;

static __device__ __forceinline__ unsigned short f2bf(float f) {
    union { float f; unsigned u; } v; v.f = f;
    unsigned r = v.u + 0x7fff + ((v.u >> 16) & 1);   // round-to-nearest-even
    return (unsigned short)(r >> 16);
}

// ---------------------------------------------------------------------------
// Fold masked 64-slot bank -> dense bf16 weights, FRAGMENT-ORDER layout:
//   chunk index = (tap*4 + quad)*64 + oc   (16 B chunks of 8 channels)
// slot j feeds channel j%32, active iff j < cn[oc].
// ---------------------------------------------------------------------------
__global__ void fold_bf16(const float* __restrict__ w,
                          const int* __restrict__ cn,
                          unsigned short* __restrict__ wk) {
    int idx = blockIdx.x * 256 + threadIdx.x;        // over 9*64*32 = 18432
    if (idx >= 9 * COUT * CIN) return;
    int c   = idx & 31;
    int oc  = (idx >> 5) & 63;
    int tap = idx >> 11;
    int n = cn[oc];
    float v = 0.0f;
    if (c < n)      v += w[(oc * MAXCN + c) * 9 + tap];
    if (c + 32 < n) v += w[(oc * MAXCN + c + 32) * 9 + tap];
    wk[((tap * 4 + (c >> 3)) * 64 + oc) * 8 + (c & 7)] = f2bf(v);
}

// ---------------------------------------------------------------------------
// x [B][C][H][W] fp32 -> xb [B][H][W][C] bf16 (NHWC).
// ---------------------------------------------------------------------------
__global__ __launch_bounds__(256)
void nchw_to_nhwc_bf16(const float* __restrict__ x,
                       unsigned short* __restrict__ xb) {
    const int b = blockIdx.y, y = blockIdx.x;
    const int t = threadIdx.x;
    const int c8  = t & 3;
    const int xi0 = t >> 2;                          // 0..63
    const float* xp = x + (size_t)b * CIN * H_ * W_ + (size_t)y * W_;
#pragma unroll
    for (int it = 0; it < 2; ++it) {
        const int xi = xi0 + it * 64;
        __align__(16) unsigned short v[8];
#pragma unroll
        for (int j = 0; j < 8; ++j) {
            const int c = c8 * 8 + j;
            v[j] = f2bf(xp[(size_t)c * (H_ * W_) + xi]);
        }
        *(uint4*)(xb + (((size_t)b * H_ + y) * W_ + xi) * CIN + c8 * 8) =
            *(const uint4*)v;
    }
}

// ---------------------------------------------------------------------------
// bias [oc][y][x] -> bnhwc [y][x][oc]  (float4-loadable, used as acc-init)
// ---------------------------------------------------------------------------
__global__ __launch_bounds__(256)
void bias_to_nhwc(const float* __restrict__ bias, float* __restrict__ bn) {
    int idx = blockIdx.x * 256 + threadIdx.x;
    int oc = idx & 63;
    int p  = idx >> 6;
    int y  = p / WO_;
    int x  = p - y * WO_;
    bn[idx] = bias[((size_t)oc * HO_ + y) * WO_ + x];
}

// ---------------------------------------------------------------------------
// Streaming implicit-GEMM conv, bf16 MFMA 16x16x32 — NO LDS, NO BARRIERS.
//   Wave = 16-pixel row segment (cols x0..x0+15) x 32 oc (ocg), marching
//   down 8 consecutive output rows. Block = 4 waves = 2 ocg x 2 row-octets
//   (16 rows x 16 cols x 64 oc). Grid (8,8,32) = 2048 blocks, 256 thr.
//   A (weights): 18 short8 frags (9 taps x 2 oc-tiles) held in REGISTERS,
//     loaded once per wave from the L2-hot 37 KB wk blob.
//   B (pixels): per tap one global_load_dwordx4 — 64 lanes = 1 KiB
//     contiguous NHWC. Row y+1,y+2 of iter i are re-read by iter i+1 ->
//     L1-hit (wave window 3.5 KB, block 7 KB, 4 blocks/CU = 28 KB <= L1;
//     R1's failure was an 86 KB footprint). One fresh row per iter.
//   Bias: NHWC float4 pair = MFMA C-init (no epilogue adds).
//   No phase gating: every wave streams loads+MFMAs independently; the
//   compiler overlaps iter i+1 loads with iter i MFMAs (no barrier stops it).
// ---------------------------------------------------------------------------
__global__ __launch_bounds__(256, 4)
void conv_mfma(const unsigned short* __restrict__ xb,
               const unsigned short* __restrict__ wk,
               const float* __restrict__ bnhwc,
               float* __restrict__ out) {
    const int strip = blockIdx.x;         // 0..7  (16-col strips)
    const int yseg  = blockIdx.y;         // 0..7  (16-row segments)
    const int img   = blockIdx.z;         // 0..31
    const int tid  = threadIdx.x;
    const int w_id = tid >> 6, lane = tid & 63;
    const int quad = lane >> 4, l16 = lane & 15;
    const int ocg  = w_id & 1;            // which 32-oc half
    const int rseg = w_id >> 1;           // which 8-row octet
    const int x0    = strip * 16;
    const int ybase = yseg * 16 + rseg * 8;
    const int col   = x0 + l16;
    const int colb  = col > (W_ - 3) ? (W_ - 3) : col;   // clamp: +kw*CIN stays in row

    // ---- A fragments to registers: 18 x b128 from fragment-order wk ----
    const short8* wq8 = (const short8*)wk;
    short8 a[9][2];
#pragma unroll
    for (int tap = 0; tap < 9; ++tap)
#pragma unroll
        for (int t = 0; t < 2; ++t)
            a[tap][t] = wq8[(tap * 4 + quad) * 64 + ocg * 32 + t * 16 + l16];

    const unsigned short* xbi = xb + (size_t)img * (H_ * W_ * CIN);
    float* ob = out + ((size_t)img * COUT + ocg * 32) * (HO_ * WO_);

    const int nit = (HO_ - ybase) < 8 ? (HO_ - ybase) : 8;   // uniform, >=1

    for (int it = 0; it < nit; ++it) {
        const int y = ybase + it;

        // ---- bias-as-accumulator-init (NHWC float4; clamped col) ----
        const int colc = col > (WO_ - 1) ? (WO_ - 1) : col;
        const float* bp = bnhwc + ((size_t)y * WO_ + colc) * COUT + ocg * 32 + quad * 4;
        floatx4 acc[2];
        {
            const float4 b0 = *(const float4*)(bp);
            const float4 b1 = *(const float4*)(bp + 16);
            acc[0] = floatx4{b0.x, b0.y, b0.z, b0.w};
            acc[1] = floatx4{b1.x, b1.y, b1.z, b1.w};
        }

        // ---- 9 taps: 3 rows x 3 kw; B frag = one b128 global load ----
#pragma unroll
        for (int r = 0; r < 3; ++r) {
            const unsigned short* prow =
                xbi + ((size_t)(y + r) * W_ + colb) * CIN + quad * 8;
            const short8 b0 = *(const short8*)(prow);
            const short8 b1 = *(const short8*)(prow + CIN);
            const short8 b2 = *(const short8*)(prow + 2 * CIN);
            acc[0] = __builtin_amdgcn_mfma_f32_16x16x32_bf16(a[r * 3 + 0][0], b0, acc[0], 0, 0, 0);
            acc[1] = __builtin_amdgcn_mfma_f32_16x16x32_bf16(a[r * 3 + 0][1], b0, acc[1], 0, 0, 0);
            acc[0] = __builtin_amdgcn_mfma_f32_16x16x32_bf16(a[r * 3 + 1][0], b1, acc[0], 0, 0, 0);
            acc[1] = __builtin_amdgcn_mfma_f32_16x16x32_bf16(a[r * 3 + 1][1], b1, acc[1], 0, 0, 0);
            acc[0] = __builtin_amdgcn_mfma_f32_16x16x32_bf16(a[r * 3 + 2][0], b2, acc[0], 0, 0, 0);
            acc[1] = __builtin_amdgcn_mfma_f32_16x16x32_bf16(a[r * 3 + 2][1], b2, acc[1], 0, 0, 0);
        }

        // ---- stores: quad-coalesced 64 B segments, guarded col only ----
        if (col < WO_) {
#pragma unroll
            for (int t = 0; t < 2; ++t)
#pragma unroll
                for (int r4 = 0; r4 < 4; ++r4) {
                    const int oc_l = t * 16 + quad * 4 + r4;
                    ob[((size_t)oc_l * HO_ + y) * WO_ + col] = acc[t][r4];
                }
        }
    }
}

// ===========================================================================
// Fallback fp32 path — used only if ws_size is too small.
// ===========================================================================
__global__ void fold_kernel(const float* __restrict__ w,
                            const int* __restrict__ cn,
                            float* __restrict__ kd) {
    int idx = blockIdx.x * blockDim.x + threadIdx.x;
    if (idx >= COUT * CIN * 9) return;
    int t = idx % 9;
    int c = (idx / 9) % CIN;
    int o = idx / (9 * CIN);
    int n = cn[o];
    float v = 0.0f;
    if (c < n)      v += w[(o * MAXCN + c) * 9 + t];
    if (c + 32 < n) v += w[(o * MAXCN + c + 32) * 9 + t];
    kd[idx] = v;
}

__global__ __launch_bounds__(256)
void conv_kernel(const float* __restrict__ x,
                 const float* __restrict__ kd,
                 const float* __restrict__ bias,
                 float* __restrict__ out) {
    __shared__ __align__(16) float xsh[CIN * 18 * 20];
    __shared__ __align__(16) float wsh[16 * 289];
    const int b = blockIdx.z, ocg = blockIdx.y, tile = blockIdx.x;
    const int ty = tile >> 3, txx = tile & 7;
    const int y0 = ty * 16, x0 = txx * 16;
    const int tid = threadIdx.x;
    const float* xbp = x + (size_t)b * CIN * H_ * W_;
    for (int idx = tid; idx < CIN * 18 * 18; idx += 256) {
        int c = idx / 324, rem = idx - c * 324, r = rem / 18, col = rem - r * 18;
        int iy = y0 + r;   if (iy > H_ - 1) iy = H_ - 1;
        int ix = x0 + col; if (ix > W_ - 1) ix = W_ - 1;
        xsh[c * 360 + r * 20 + col] = xbp[(c * H_ + iy) * W_ + ix];
    }
    for (int idx = tid; idx < 16 * 288; idx += 256) {
        int oc = idx / 288, rr = idx - oc * 288;
        wsh[oc * 289 + rr] = kd[(ocg * 16 + oc) * 288 + rr];
    }
    __syncthreads();
    const int oc_l = tid & 15, pb = tid >> 4, pby = pb >> 2, pbx = pb & 3;
    float acc[4][4];
#pragma unroll
    for (int i = 0; i < 4; ++i)
#pragma unroll
        for (int j = 0; j < 4; ++j) acc[i][j] = 0.0f;
    const float* xp = &xsh[(pby * 4) * 20 + pbx * 4];
    const float* wp = &wsh[oc_l * 289];
    for (int c = 0; c < CIN; ++c) {
        float xr[6][6];
#pragma unroll
        for (int r = 0; r < 6; ++r) {
            const float* row = xp + c * 360 + r * 20;
            float4 v4 = *reinterpret_cast<const float4*>(row);
            float2 v2 = *reinterpret_cast<const float2*>(row + 4);
            xr[r][0] = v4.x; xr[r][1] = v4.y; xr[r][2] = v4.z;
            xr[r][3] = v4.w; xr[r][4] = v2.x; xr[r][5] = v2.y;
        }
        float wr[9];
#pragma unroll
        for (int t = 0; t < 9; ++t) wr[t] = wp[c * 9 + t];
#pragma unroll
        for (int kh = 0; kh < 3; ++kh)
#pragma unroll
            for (int kw = 0; kw < 3; ++kw) {
                const float wv = wr[kh * 3 + kw];
#pragma unroll
                for (int i = 0; i < 4; ++i)
#pragma unroll
                    for (int j = 0; j < 4; ++j)
                        acc[i][j] = fmaf(xr[i + kh][j + kw], wv, acc[i][j]);
            }
    }
    const int o = ocg * 16 + oc_l;
    const int yb = y0 + pby * 4, xq0 = x0 + pbx * 4;
    float* ob = out + ((size_t)(b * COUT + o)) * HO_ * WO_;
    const float* bb = bias + (size_t)o * HO_ * WO_;
#pragma unroll
    for (int i = 0; i < 4; ++i) {
        int y = yb + i;
        if (y >= HO_) continue;
#pragma unroll
        for (int j = 0; j < 4; ++j) {
            int xq = xq0 + j;
            if (xq >= WO_) continue;
            ob[y * WO_ + xq] = acc[i][j] + bb[y * WO_ + xq];
        }
    }
}

extern "C" void kernel_launch(void* const* d_in, const int* in_sizes, int n_in,
                              void* d_out, int out_size, void* d_ws, size_t ws_size,
                              hipStream_t stream) {
    const float* x    = (const float*)d_in[0];
    const float* w    = (const float*)d_in[1];
    const float* bias = (const float*)d_in[2];
    const int*   cn   = (const int*)d_in[3];
    float* out = (float*)d_out;

    const size_t XB_BYTES = (size_t)B_ * H_ * W_ * CIN * 2;   // 33554432
    const size_t WK_BYTES = (size_t)9 * COUT * CIN * 2;       // 36864
    const size_t BN_BYTES = (size_t)HO_ * WO_ * COUT * 4;     // 4064256

    if (ws_size >= XB_BYTES + WK_BYTES + BN_BYTES) {
        unsigned short* xbuf = (unsigned short*)d_ws;
        unsigned short* wkb  = (unsigned short*)((char*)d_ws + XB_BYTES);
        float*          bnb  = (float*)((char*)d_ws + XB_BYTES + WK_BYTES);
        fold_bf16<<<72, 256, 0, stream>>>(w, cn, wkb);
        nchw_to_nhwc_bf16<<<dim3(H_, B_), 256, 0, stream>>>(x, xbuf);
        bias_to_nhwc<<<3969, 256, 0, stream>>>(bias, bnb);
        conv_mfma<<<dim3(8, 8, B_), 256, 0, stream>>>(xbuf, wkb, bnb, out);
    } else {
        float* kd = (float*)d_ws;                             // 73728 B
        fold_kernel<<<(COUT * CIN * 9 + 255) / 256, 256, 0, stream>>>(w, cn, kd);
        dim3 grid(64, 4, B_);
        conv_kernel<<<grid, 256, 0, stream>>>(x, kd, bias, out);
    }
}

// Round 7
// 279.754 us; speedup vs baseline: 1.1117x; 1.0303x over previous
//
#include <hip/hip_runtime.h>

// Problem dims
#define B_    32
#define CIN   32
#define COUT  64
#define H_    128
#define W_    128
#define HO_   126
#define WO_   126
#define MAXCN 64

typedef __attribute__((ext_vector_type(8))) short short8;
typedef __attribute__((ext_vector_type(4))) float floatx4;

static __device__ __forceinline__ unsigned short f2bf(float f) {
    union { float f; unsigned u; } v; v.f = f;
    unsigned r = v.u + 0x7fff + ((v.u >> 16) & 1);   // round-to-nearest-even
    return (unsigned short)(r >> 16);
}

// ---------------------------------------------------------------------------
// prep: fused fold + bias transpose (one launch instead of two).
//   blocks [0,72):    fold masked 64-slot bank -> dense bf16 weights in
//                     FRAGMENT-ORDER chunks: (tap*4+quad)*64 + oc
//   blocks [72,4041): bias [oc][y][x] -> bnhwc [y][x][oc]
// ---------------------------------------------------------------------------
__global__ __launch_bounds__(256)
void prep(const float* __restrict__ w, const int* __restrict__ cn,
          unsigned short* __restrict__ wk,
          const float* __restrict__ bias, float* __restrict__ bn) {
    const int bid = blockIdx.x;
    if (bid < 72) {
        int idx = bid * 256 + threadIdx.x;           // over 9*64*32 = 18432
        if (idx >= 9 * COUT * CIN) return;
        int c   = idx & 31;
        int oc  = (idx >> 5) & 63;
        int tap = idx >> 11;
        int n = cn[oc];
        float v = 0.0f;
        if (c < n)      v += w[(oc * MAXCN + c) * 9 + tap];
        if (c + 32 < n) v += w[(oc * MAXCN + c + 32) * 9 + tap];
        wk[((tap * 4 + (c >> 3)) * 64 + oc) * 8 + (c & 7)] = f2bf(v);
    } else {
        int idx = (bid - 72) * 256 + threadIdx.x;    // over 126*126*64
        int oc = idx & 63;
        int p  = idx >> 6;
        int y  = p / WO_;
        int x  = p - y * WO_;
        bn[idx] = bias[((size_t)oc * HO_ + y) * WO_ + x];
    }
}

// ---------------------------------------------------------------------------
// x [B][C][H][W] fp32 -> xb [B][H][W][C] bf16 (NHWC).
// ---------------------------------------------------------------------------
__global__ __launch_bounds__(256)
void nchw_to_nhwc_bf16(const float* __restrict__ x,
                       unsigned short* __restrict__ xb) {
    const int b = blockIdx.y, y = blockIdx.x;
    const int t = threadIdx.x;
    const int c8  = t & 3;
    const int xi0 = t >> 2;                          // 0..63
    const float* xp = x + (size_t)b * CIN * H_ * W_ + (size_t)y * W_;
#pragma unroll
    for (int it = 0; it < 2; ++it) {
        const int xi = xi0 + it * 64;
        __align__(16) unsigned short v[8];
#pragma unroll
        for (int j = 0; j < 8; ++j) {
            const int c = c8 * 8 + j;
            v[j] = f2bf(xp[(size_t)c * (H_ * W_) + xi]);
        }
        *(uint4*)(xb + (((size_t)b * H_ + y) * W_ + xi) * CIN + c8 * 8) =
            *(const uint4*)v;
    }
}

// ---------------------------------------------------------------------------
// Streaming implicit-GEMM conv, bf16 MFMA 16x16x32 — NO LDS, NO BARRIERS.
//   Wave = 16-px row segment x 32 oc, marching down 8 rows. Same math as R6
//   (which verified), restructured for register residency:
//   * A (18 short8 = 72 VGPR) loaded ONCE and PINNED via empty volatile asm
//     (opaque to remat). R6's VGPR=60 proved the compiler was re-loading all
//     18 A-frags every iteration under the 128-VGPR cap -> 37 VMEM/iter,
//     L2-latency-bound. __launch_bounds__(256,3) raises the cap to 170.
//   * B rolling window bw[4][3] (48 VGPR): rows y..y+2 stay in regs across
//     iters; each iter prefetches only row y+3 (3 loads) consumed NEXT iter
//     -> latency hidden under 18 MFMAs + stores. Full unroll keeps all
//     window indices compile-time (no scratch).
//   Per-iter VMEM: 3 B + 2 bias + 8 stores = 13 (was ~37).
// ---------------------------------------------------------------------------
__global__ __launch_bounds__(256, 3)
void conv_mfma(const unsigned short* __restrict__ xb,
               const unsigned short* __restrict__ wk,
               const float* __restrict__ bnhwc,
               float* __restrict__ out) {
    const int strip = blockIdx.x;         // 0..7  (16-col strips)
    const int yseg  = blockIdx.y;         // 0..7  (16-row segments)
    const int img   = blockIdx.z;         // 0..31
    const int tid  = threadIdx.x;
    const int w_id = tid >> 6, lane = tid & 63;
    const int quad = lane >> 4, l16 = lane & 15;
    const int ocg  = w_id & 1;            // which 32-oc half
    const int rseg = w_id >> 1;           // which 8-row octet
    const int x0    = strip * 16;
    const int ybase = yseg * 16 + rseg * 8;
    const int col   = x0 + l16;
    const int colb  = col > (W_ - 3) ? (W_ - 3) : col;   // +2*CIN stays in row
    const int colc  = col > (WO_ - 1) ? (WO_ - 1) : col;

    // ---- A fragments: load once, PIN in registers ----
    const short8* wq8 = (const short8*)wk;
    short8 a[9][2];
#pragma unroll
    for (int tap = 0; tap < 9; ++tap)
#pragma unroll
        for (int t = 0; t < 2; ++t)
            a[tap][t] = wq8[(tap * 4 + quad) * 64 + ocg * 32 + t * 16 + l16];
#pragma unroll
    for (int tap = 0; tap < 9; ++tap)
#pragma unroll
        for (int t = 0; t < 2; ++t)
            asm volatile("" : "+v"(a[tap][t]));      // opaque: no remat/reload

    const unsigned short* xbi = xb + (size_t)img * (H_ * W_ * CIN);
    float* ob = out + ((size_t)img * COUT + ocg * 32) * (HO_ * WO_);

    const int nit = (HO_ - ybase) < 8 ? (HO_ - ybase) : 8;   // wave-uniform

    if (nit == 8) {
        // ---- rolling 4-slot B window; prologue rows 0..2 ----
        short8 bw[4][3];
#pragma unroll
        for (int r = 0; r < 3; ++r) {
            const unsigned short* prow =
                xbi + ((size_t)(ybase + r) * W_ + colb) * CIN + quad * 8;
            bw[r][0] = *(const short8*)(prow);
            bw[r][1] = *(const short8*)(prow + CIN);
            bw[r][2] = *(const short8*)(prow + 2 * CIN);
        }
#pragma unroll
        for (int it = 0; it < 8; ++it) {
            const int y = ybase + it;
            // prefetch row y+3 into slot (it+3)&3 (used next iter)
            if (it < 7) {
                const unsigned short* prow =
                    xbi + ((size_t)(y + 3) * W_ + colb) * CIN + quad * 8;
                const int s = (it + 3) & 3;
                bw[s][0] = *(const short8*)(prow);
                bw[s][1] = *(const short8*)(prow + CIN);
                bw[s][2] = *(const short8*)(prow + 2 * CIN);
            }
            // bias-as-accumulator-init
            const float* bp = bnhwc + ((size_t)y * WO_ + colc) * COUT + ocg * 32 + quad * 4;
            const float4 b0 = *(const float4*)(bp);
            const float4 b1 = *(const float4*)(bp + 16);
            floatx4 acc0 = floatx4{b0.x, b0.y, b0.z, b0.w};
            floatx4 acc1 = floatx4{b1.x, b1.y, b1.z, b1.w};
#pragma unroll
            for (int r = 0; r < 3; ++r) {
                const int s = (it + r) & 3;
                acc0 = __builtin_amdgcn_mfma_f32_16x16x32_bf16(a[r * 3 + 0][0], bw[s][0], acc0, 0, 0, 0);
                acc1 = __builtin_amdgcn_mfma_f32_16x16x32_bf16(a[r * 3 + 0][1], bw[s][0], acc1, 0, 0, 0);
                acc0 = __builtin_amdgcn_mfma_f32_16x16x32_bf16(a[r * 3 + 1][0], bw[s][1], acc0, 0, 0, 0);
                acc1 = __builtin_amdgcn_mfma_f32_16x16x32_bf16(a[r * 3 + 1][1], bw[s][1], acc1, 0, 0, 0);
                acc0 = __builtin_amdgcn_mfma_f32_16x16x32_bf16(a[r * 3 + 2][0], bw[s][2], acc0, 0, 0, 0);
                acc1 = __builtin_amdgcn_mfma_f32_16x16x32_bf16(a[r * 3 + 2][1], bw[s][2], acc1, 0, 0, 0);
            }
            if (col < WO_) {
#pragma unroll
                for (int r4 = 0; r4 < 4; ++r4) {
                    const int o0 = quad * 4 + r4;
                    ob[((size_t)o0 * HO_ + y) * WO_ + col] = acc0[r4];
                    ob[((size_t)(16 + o0) * HO_ + y) * WO_ + col] = acc1[r4];
                }
            }
        }
    } else {
        // ---- short tail (ybase=120 waves only): simple per-iter reload ----
        for (int it = 0; it < nit; ++it) {
            const int y = ybase + it;
            const float* bp = bnhwc + ((size_t)y * WO_ + colc) * COUT + ocg * 32 + quad * 4;
            const float4 b0 = *(const float4*)(bp);
            const float4 b1 = *(const float4*)(bp + 16);
            floatx4 acc0 = floatx4{b0.x, b0.y, b0.z, b0.w};
            floatx4 acc1 = floatx4{b1.x, b1.y, b1.z, b1.w};
#pragma unroll
            for (int r = 0; r < 3; ++r) {
                const unsigned short* prow =
                    xbi + ((size_t)(y + r) * W_ + colb) * CIN + quad * 8;
                const short8 v0 = *(const short8*)(prow);
                const short8 v1 = *(const short8*)(prow + CIN);
                const short8 v2 = *(const short8*)(prow + 2 * CIN);
                acc0 = __builtin_amdgcn_mfma_f32_16x16x32_bf16(a[r * 3 + 0][0], v0, acc0, 0, 0, 0);
                acc1 = __builtin_amdgcn_mfma_f32_16x16x32_bf16(a[r * 3 + 0][1], v0, acc1, 0, 0, 0);
                acc0 = __builtin_amdgcn_mfma_f32_16x16x32_bf16(a[r * 3 + 1][0], v1, acc0, 0, 0, 0);
                acc1 = __builtin_amdgcn_mfma_f32_16x16x32_bf16(a[r * 3 + 1][1], v1, acc1, 0, 0, 0);
                acc0 = __builtin_amdgcn_mfma_f32_16x16x32_bf16(a[r * 3 + 2][0], v2, acc0, 0, 0, 0);
                acc1 = __builtin_amdgcn_mfma_f32_16x16x32_bf16(a[r * 3 + 2][1], v2, acc1, 0, 0, 0);
            }
            if (col < WO_) {
#pragma unroll
                for (int r4 = 0; r4 < 4; ++r4) {
                    const int o0 = quad * 4 + r4;
                    ob[((size_t)o0 * HO_ + y) * WO_ + col] = acc0[r4];
                    ob[((size_t)(16 + o0) * HO_ + y) * WO_ + col] = acc1[r4];
                }
            }
        }
    }
}

// ===========================================================================
// Fallback fp32 path — used only if ws_size is too small.
// ===========================================================================
__global__ void fold_kernel(const float* __restrict__ w,
                            const int* __restrict__ cn,
                            float* __restrict__ kd) {
    int idx = blockIdx.x * blockDim.x + threadIdx.x;
    if (idx >= COUT * CIN * 9) return;
    int t = idx % 9;
    int c = (idx / 9) % CIN;
    int o = idx / (9 * CIN);
    int n = cn[o];
    float v = 0.0f;
    if (c < n)      v += w[(o * MAXCN + c) * 9 + t];
    if (c + 32 < n) v += w[(o * MAXCN + c + 32) * 9 + t];
    kd[idx] = v;
}

__global__ __launch_bounds__(256)
void conv_kernel(const float* __restrict__ x,
                 const float* __restrict__ kd,
                 const float* __restrict__ bias,
                 float* __restrict__ out) {
    __shared__ __align__(16) float xsh[CIN * 18 * 20];
    __shared__ __align__(16) float wsh[16 * 289];
    const int b = blockIdx.z, ocg = blockIdx.y, tile = blockIdx.x;
    const int ty = tile >> 3, txx = tile & 7;
    const int y0 = ty * 16, x0 = txx * 16;
    const int tid = threadIdx.x;
    const float* xbp = x + (size_t)b * CIN * H_ * W_;
    for (int idx = tid; idx < CIN * 18 * 18; idx += 256) {
        int c = idx / 324, rem = idx - c * 324, r = rem / 18, col = rem - r * 18;
        int iy = y0 + r;   if (iy > H_ - 1) iy = H_ - 1;
        int ix = x0 + col; if (ix > W_ - 1) ix = W_ - 1;
        xsh[c * 360 + r * 20 + col] = xbp[(c * H_ + iy) * W_ + ix];
    }
    for (int idx = tid; idx < 16 * 288; idx += 256) {
        int oc = idx / 288, rr = idx - oc * 288;
        wsh[oc * 289 + rr] = kd[(ocg * 16 + oc) * 288 + rr];
    }
    __syncthreads();
    const int oc_l = tid & 15, pb = tid >> 4, pby = pb >> 2, pbx = pb & 3;
    float acc[4][4];
#pragma unroll
    for (int i = 0; i < 4; ++i)
#pragma unroll
        for (int j = 0; j < 4; ++j) acc[i][j] = 0.0f;
    const float* xp = &xsh[(pby * 4) * 20 + pbx * 4];
    const float* wp = &wsh[oc_l * 289];
    for (int c = 0; c < CIN; ++c) {
        float xr[6][6];
#pragma unroll
        for (int r = 0; r < 6; ++r) {
            const float* row = xp + c * 360 + r * 20;
            float4 v4 = *reinterpret_cast<const float4*>(row);
            float2 v2 = *reinterpret_cast<const float2*>(row + 4);
            xr[r][0] = v4.x; xr[r][1] = v4.y; xr[r][2] = v4.z;
            xr[r][3] = v4.w; xr[r][4] = v2.x; xr[r][5] = v2.y;
        }
        float wr[9];
#pragma unroll
        for (int t = 0; t < 9; ++t) wr[t] = wp[c * 9 + t];
#pragma unroll
        for (int kh = 0; kh < 3; ++kh)
#pragma unroll
            for (int kw = 0; kw < 3; ++kw) {
                const float wv = wr[kh * 3 + kw];
#pragma unroll
                for (int i = 0; i < 4; ++i)
#pragma unroll
                    for (int j = 0; j < 4; ++j)
                        acc[i][j] = fmaf(xr[i + kh][j + kw], wv, acc[i][j]);
            }
    }
    const int o = ocg * 16 + oc_l;
    const int yb = y0 + pby * 4, xq0 = x0 + pbx * 4;
    float* ob = out + ((size_t)(b * COUT + o)) * HO_ * WO_;
    const float* bb = bias + (size_t)o * HO_ * WO_;
#pragma unroll
    for (int i = 0; i < 4; ++i) {
        int y = yb + i;
        if (y >= HO_) continue;
#pragma unroll
        for (int j = 0; j < 4; ++j) {
            int xq = xq0 + j;
            if (xq >= WO_) continue;
            ob[y * WO_ + xq] = acc[i][j] + bb[y * WO_ + xq];
        }
    }
}

extern "C" void kernel_launch(void* const* d_in, const int* in_sizes, int n_in,
                              void* d_out, int out_size, void* d_ws, size_t ws_size,
                              hipStream_t stream) {
    const float* x    = (const float*)d_in[0];
    const float* w    = (const float*)d_in[1];
    const float* bias = (const float*)d_in[2];
    const int*   cn   = (const int*)d_in[3];
    float* out = (float*)d_out;

    const size_t XB_BYTES = (size_t)B_ * H_ * W_ * CIN * 2;   // 33554432
    const size_t WK_BYTES = (size_t)9 * COUT * CIN * 2;       // 36864
    const size_t BN_BYTES = (size_t)HO_ * WO_ * COUT * 4;     // 4064256

    if (ws_size >= XB_BYTES + WK_BYTES + BN_BYTES) {
        unsigned short* xbuf = (unsigned short*)d_ws;
        unsigned short* wkb  = (unsigned short*)((char*)d_ws + XB_BYTES);
        float*          bnb  = (float*)((char*)d_ws + XB_BYTES + WK_BYTES);
        prep<<<72 + 3969, 256, 0, stream>>>(w, cn, wkb, bias, bnb);
        nchw_to_nhwc_bf16<<<dim3(H_, B_), 256, 0, stream>>>(x, xbuf);
        conv_mfma<<<dim3(8, 8, B_), 256, 0, stream>>>(xbuf, wkb, bnb, out);
    } else {
        float* kd = (float*)d_ws;                             // 73728 B
        fold_kernel<<<(COUT * CIN * 9 + 255) / 256, 256, 0, stream>>>(w, cn, kd);
        dim3 grid(64, 4, B_);
        conv_kernel<<<grid, 256, 0, stream>>>(x, kd, bias, out);
    }
}

// Round 8
// 273.765 us; speedup vs baseline: 1.1361x; 1.0219x over previous
//
#include <hip/hip_runtime.h>

// Problem dims
#define B_    32
#define CIN   32
#define COUT  64
#define H_    128
#define W_    128
#define HO_   126
#define WO_   126
#define MAXCN 64

typedef __attribute__((ext_vector_type(8))) short short8;
typedef __attribute__((ext_vector_type(4))) float floatx4;

static __device__ __forceinline__ unsigned short f2bf(float f) {
    union { float f; unsigned u; } v; v.f = f;
    unsigned r = v.u + 0x7fff + ((v.u >> 16) & 1);   // round-to-nearest-even
    return (unsigned short)(r >> 16);
}

// ---------------------------------------------------------------------------
// Fold masked 64-slot bank -> dense bf16 weights, FRAGMENT-ORDER layout:
//   chunk index = (tap*4 + quad)*64 + oc   (16 B chunks of 8 channels)
// slot j feeds channel j%32, active iff j < cn[oc].
// ---------------------------------------------------------------------------
__global__ void fold_bf16(const float* __restrict__ w,
                          const int* __restrict__ cn,
                          unsigned short* __restrict__ wk) {
    int idx = blockIdx.x * 256 + threadIdx.x;        // over 9*64*32 = 18432
    if (idx >= 9 * COUT * CIN) return;
    int c   = idx & 31;
    int oc  = (idx >> 5) & 63;
    int tap = idx >> 11;
    int n = cn[oc];
    float v = 0.0f;
    if (c < n)      v += w[(oc * MAXCN + c) * 9 + tap];
    if (c + 32 < n) v += w[(oc * MAXCN + c + 32) * 9 + tap];
    wk[((tap * 4 + (c >> 3)) * 64 + oc) * 8 + (c & 7)] = f2bf(v);
}

// ---------------------------------------------------------------------------
// x [B][C][H][W] fp32 -> xb [B][H][W][C] bf16 (NHWC).
// ---------------------------------------------------------------------------
__global__ __launch_bounds__(256)
void nchw_to_nhwc_bf16(const float* __restrict__ x,
                       unsigned short* __restrict__ xb) {
    const int b = blockIdx.y, y = blockIdx.x;
    const int t = threadIdx.x;
    const int c8  = t & 3;
    const int xi0 = t >> 2;                          // 0..63
    const float* xp = x + (size_t)b * CIN * H_ * W_ + (size_t)y * W_;
#pragma unroll
    for (int it = 0; it < 2; ++it) {
        const int xi = xi0 + it * 64;
        __align__(16) unsigned short v[8];
#pragma unroll
        for (int j = 0; j < 8; ++j) {
            const int c = c8 * 8 + j;
            v[j] = f2bf(xp[(size_t)c * (H_ * W_) + xi]);
        }
        *(uint4*)(xb + (((size_t)b * H_ + y) * W_ + xi) * CIN + c8 * 8) =
            *(const uint4*)v;
    }
}

// ---------------------------------------------------------------------------
// Streaming implicit-GEMM conv — OPERAND-SWAPPED MFMA for full-line writes.
//   mfma(pixels, weights, acc): C row = PIXEL (quad*4+reg), col = OC (l16).
//   Each lane's floatx4 = 4 consecutive x for ONE oc -> one dwordx4 store;
//   a wave's two 16-px tiles write full 128-B lines per oc-plane. This kills
//   the 1.35x partial-line write amplification (WRITE_SIZE 175 MB for a
//   130 MB tensor) that pinned every prior design at ~2.1-2.5 TB/s.
//   Wave = 32 px x 16 oc x 16 rows. Block = 4 waves (64 oc). Grid (4,8,32).
//   A (weights) = 9 short8 = 36 VGPR, loaded once, pinned (fits 128 cap ->
//   no remat, no AGPR parking). B (pixels) from global NHWC, L1-served
//   re-reads (proven R6: FETCH ~30 MB, 0 conflicts). Bias read DIRECTLY from
//   original [oc][y][x] layout as float4 acc-init (no bias transpose pass).
//   Overlap-padded tiling: x0 in {0,32,64,94}, y0 in {0,16,...,96,110} ->
//   no guards anywhere; overlapped cells double-write identical values.
//   x0=94 strip is 8-B (not 16-B) aligned -> block-uniform float2 path.
// ---------------------------------------------------------------------------
__global__ __launch_bounds__(256)
void conv_mfma(const unsigned short* __restrict__ xb,
               const unsigned short* __restrict__ wk,
               const float* __restrict__ bias,
               float* __restrict__ out) {
    const int strip = blockIdx.x;         // 0..3
    const int yseg  = blockIdx.y;         // 0..7
    const int img   = blockIdx.z;         // 0..31
    int x0 = strip * 32; if (x0 > 94) x0 = 94;      // strip 3 -> 94..125
    int y0 = yseg * 16;  if (y0 > 110) y0 = 110;    // yseg 7  -> 110..125
    const int tid  = threadIdx.x;
    const int w_id = tid >> 6, lane = tid & 63;
    const int quad = lane >> 4, l16 = lane & 15;
    const int ocb  = w_id * 16;

    // ---- A (weights) as SECOND operand: lane l16 = oc, quad = k-chunk ----
    const short8* wq8 = (const short8*)wk;
    short8 wfrag[9];
#pragma unroll
    for (int tap = 0; tap < 9; ++tap)
        wfrag[tap] = wq8[(tap * 4 + quad) * 64 + ocb + l16];
#pragma unroll
    for (int tap = 0; tap < 9; ++tap)
        asm volatile("" : "+v"(wfrag[tap]));         // no remat/reload

    const unsigned short* xbi = xb + (size_t)img * (H_ * W_ * CIN);
    // per-lane bias/out base: oc-plane = ocb+l16, x = x0 + quad*4 (+tile*16)
    const float* bp0 = bias + ((size_t)(ocb + l16) * HO_ + y0) * WO_ + x0 + quad * 4;
    float* op0 = out + (((size_t)(img * COUT + ocb + l16)) * HO_ + y0) * WO_ + x0 + quad * 4;
    const bool aligned = (x0 & 3) == 0;              // block-uniform

    for (int it = 0; it < 16; ++it) {
        const int y = y0 + it;
        const float* bp = bp0 + it * WO_;
        float* op = op0 + it * WO_;

        // ---- bias-as-accumulator-init (original [oc][y][x] layout) ----
        floatx4 acc0, acc1;
        if (aligned) {
            const float4 b0 = *(const float4*)(bp);
            const float4 b1 = *(const float4*)(bp + 16);
            acc0 = floatx4{b0.x, b0.y, b0.z, b0.w};
            acc1 = floatx4{b1.x, b1.y, b1.z, b1.w};
        } else {
            const float2 b0a = *(const float2*)(bp);
            const float2 b0b = *(const float2*)(bp + 2);
            const float2 b1a = *(const float2*)(bp + 16);
            const float2 b1b = *(const float2*)(bp + 18);
            acc0 = floatx4{b0a.x, b0a.y, b0b.x, b0b.y};
            acc1 = floatx4{b1a.x, b1a.y, b1b.x, b1b.y};
        }

        // ---- 9 taps: pixels as FIRST operand (row = px = l16 + kw shift) ----
#pragma unroll
        for (int r = 0; r < 3; ++r) {
            const unsigned short* prow =
                xbi + ((size_t)(y + r) * W_ + x0 + l16) * CIN + quad * 8;
#pragma unroll
            for (int kw = 0; kw < 3; ++kw) {
                const short8 p0 = *(const short8*)(prow + kw * CIN);
                const short8 p1 = *(const short8*)(prow + (16 + kw) * CIN);
                acc0 = __builtin_amdgcn_mfma_f32_16x16x32_bf16(p0, wfrag[r * 3 + kw], acc0, 0, 0, 0);
                acc1 = __builtin_amdgcn_mfma_f32_16x16x32_bf16(p1, wfrag[r * 3 + kw], acc1, 0, 0, 0);
            }
        }

        // ---- stores: 4 consecutive x per lane, full-line merged per oc ----
        if (aligned) {
            *(floatx4*)(op)      = acc0;
            *(floatx4*)(op + 16) = acc1;
        } else {
            *(float2*)(op)      = float2{acc0[0], acc0[1]};
            *(float2*)(op + 2)  = float2{acc0[2], acc0[3]};
            *(float2*)(op + 16) = float2{acc1[0], acc1[1]};
            *(float2*)(op + 18) = float2{acc1[2], acc1[3]};
        }
    }
}

// ===========================================================================
// Fallback fp32 path — used only if ws_size is too small.
// ===========================================================================
__global__ void fold_kernel(const float* __restrict__ w,
                            const int* __restrict__ cn,
                            float* __restrict__ kd) {
    int idx = blockIdx.x * blockDim.x + threadIdx.x;
    if (idx >= COUT * CIN * 9) return;
    int t = idx % 9;
    int c = (idx / 9) % CIN;
    int o = idx / (9 * CIN);
    int n = cn[o];
    float v = 0.0f;
    if (c < n)      v += w[(o * MAXCN + c) * 9 + t];
    if (c + 32 < n) v += w[(o * MAXCN + c + 32) * 9 + t];
    kd[idx] = v;
}

__global__ __launch_bounds__(256)
void conv_kernel(const float* __restrict__ x,
                 const float* __restrict__ kd,
                 const float* __restrict__ bias,
                 float* __restrict__ out) {
    __shared__ __align__(16) float xsh[CIN * 18 * 20];
    __shared__ __align__(16) float wsh[16 * 289];
    const int b = blockIdx.z, ocg = blockIdx.y, tile = blockIdx.x;
    const int ty = tile >> 3, txx = tile & 7;
    const int y0 = ty * 16, x0 = txx * 16;
    const int tid = threadIdx.x;
    const float* xbp = x + (size_t)b * CIN * H_ * W_;
    for (int idx = tid; idx < CIN * 18 * 18; idx += 256) {
        int c = idx / 324, rem = idx - c * 324, r = rem / 18, col = rem - r * 18;
        int iy = y0 + r;   if (iy > H_ - 1) iy = H_ - 1;
        int ix = x0 + col; if (ix > W_ - 1) ix = W_ - 1;
        xsh[c * 360 + r * 20 + col] = xbp[(c * H_ + iy) * W_ + ix];
    }
    for (int idx = tid; idx < 16 * 288; idx += 256) {
        int oc = idx / 288, rr = idx - oc * 288;
        wsh[oc * 289 + rr] = kd[(ocg * 16 + oc) * 288 + rr];
    }
    __syncthreads();
    const int oc_l = tid & 15, pb = tid >> 4, pby = pb >> 2, pbx = pb & 3;
    float acc[4][4];
#pragma unroll
    for (int i = 0; i < 4; ++i)
#pragma unroll
        for (int j = 0; j < 4; ++j) acc[i][j] = 0.0f;
    const float* xp = &xsh[(pby * 4) * 20 + pbx * 4];
    const float* wp = &wsh[oc_l * 289];
    for (int c = 0; c < CIN; ++c) {
        float xr[6][6];
#pragma unroll
        for (int r = 0; r < 6; ++r) {
            const float* row = xp + c * 360 + r * 20;
            float4 v4 = *reinterpret_cast<const float4*>(row);
            float2 v2 = *reinterpret_cast<const float2*>(row + 4);
            xr[r][0] = v4.x; xr[r][1] = v4.y; xr[r][2] = v4.z;
            xr[r][3] = v4.w; xr[r][4] = v2.x; xr[r][5] = v2.y;
        }
        float wr[9];
#pragma unroll
        for (int t = 0; t < 9; ++t) wr[t] = wp[c * 9 + t];
#pragma unroll
        for (int kh = 0; kh < 3; ++kh)
#pragma unroll
            for (int kw = 0; kw < 3; ++kw) {
                const float wv = wr[kh * 3 + kw];
#pragma unroll
                for (int i = 0; i < 4; ++i)
#pragma unroll
                    for (int j = 0; j < 4; ++j)
                        acc[i][j] = fmaf(xr[i + kh][j + kw], wv, acc[i][j]);
            }
    }
    const int o = ocg * 16 + oc_l;
    const int yb = y0 + pby * 4, xq0 = x0 + pbx * 4;
    float* ob = out + ((size_t)(b * COUT + o)) * HO_ * WO_;
    const float* bb = bias + (size_t)o * HO_ * WO_;
#pragma unroll
    for (int i = 0; i < 4; ++i) {
        int y = yb + i;
        if (y >= HO_) continue;
#pragma unroll
        for (int j = 0; j < 4; ++j) {
            int xq = xq0 + j;
            if (xq >= WO_) continue;
            ob[y * WO_ + xq] = acc[i][j] + bb[y * WO_ + xq];
        }
    }
}

extern "C" void kernel_launch(void* const* d_in, const int* in_sizes, int n_in,
                              void* d_out, int out_size, void* d_ws, size_t ws_size,
                              hipStream_t stream) {
    const float* x    = (const float*)d_in[0];
    const float* w    = (const float*)d_in[1];
    const float* bias = (const float*)d_in[2];
    const int*   cn   = (const int*)d_in[3];
    float* out = (float*)d_out;

    const size_t XB_BYTES = (size_t)B_ * H_ * W_ * CIN * 2;   // 33554432
    const size_t WK_BYTES = (size_t)9 * COUT * CIN * 2;       // 36864

    if (ws_size >= XB_BYTES + WK_BYTES) {
        unsigned short* xbuf = (unsigned short*)d_ws;
        unsigned short* wkb  = (unsigned short*)((char*)d_ws + XB_BYTES);
        fold_bf16<<<72, 256, 0, stream>>>(w, cn, wkb);
        nchw_to_nhwc_bf16<<<dim3(H_, B_), 256, 0, stream>>>(x, xbuf);
        conv_mfma<<<dim3(4, 8, B_), 256, 0, stream>>>(xbuf, wkb, bias, out);
    } else {
        float* kd = (float*)d_ws;                             // 73728 B
        fold_kernel<<<(COUT * CIN * 9 + 255) / 256, 256, 0, stream>>>(w, cn, kd);
        dim3 grid(64, 4, B_);
        conv_kernel<<<grid, 256, 0, stream>>>(x, kd, bias, out);
    }
}